// Round 15
// baseline (974.860 us; speedup 1.0000x reference)
//
#include <hip/hip_runtime.h>
#include <math.h>

#define G 4
#define NT 256

// fp32 problem (validated). G=4 batches per block.
//
// Hard-won configuration facts (measured r2-r14):
//  - G=4, NT=256, __launch_bounds__(256,4). NT=512 pins VGPR at the cap ->
//    GBs of scratch spill (r3/r4). G=2 -> invisible scratch (r7).
//  - Scratch demotion triggers: SEQUENTIAL agg bodies in one path (r8) and
//    MIXED sub/parent templates in one kernel (r12 k_lvl1). SAME-template
//    branching on blockIdx.y is clean (r2, r14 merged parents: FETCH 35MB).
//  - Weight access per-wave COALESCED (lane = fastest dim). r6: gathers +50%.
//    r10: Wv/Wo gather->coalesced (k_setup transpose) won 196->181us.
//  - attn/FFN kernel split REGRESSED (r11). Wave-parallel softmax + pal-fold
//    combo REGRESSED (r12/r13); reverted to serial softmax + separate k_pal.
//  - Partial/reduce scheme for Wv/Wo/W2 kept: direct per-(e,g) mapping would
//    2-4x weight L2 traffic (~+68us) vs ~8KB partial round-trip. Keep.
//  - X layout [g][s][XP], XP=68/132 (row stride == 4 mod 32 banks).
//  - q/u/sb + WvT/WoT precomputed once per launch in k_setup.
//  - THIS ROUND (r14 + one change): xbar phase vectorized to float4 —
//    was 128 scalar ds_read_b32/thread (E=128), now 32 ds_read_b128.
//    LDS pipe is the serializer (VALUBusy plateaus ~50%).

enum {
  I_LEAF = 0, I_SUB, I_SAW, I_SAB, I_LAW, I_LAB, I_PAW, I_PAB,
  I_SCLS, I_SWQKV, I_SBQKV, I_SWO, I_SBO, I_SLNG, I_SLNB, I_SW1, I_SB1, I_SW2, I_SB2,
  I_PCLS, I_PWQKV, I_PBQKV, I_PWO, I_PBO, I_PLNG, I_PLNB, I_PW1, I_PB1, I_PW2, I_PB2,
  I_CLFW, I_CLFB
};

struct P {
  const float* in[32];
  float* parent_al;  // ws [B][2][128]
  float* vecs;       // ws [B][3][128]; slot0: tcpf|ipf until k_pal, then eth
  float* out;        // [B][2]
};

// per-aggregator precomputed query side: u[4][E] then sb[4] at offset 4*E.
// aggs: 0,1 = sub (E=64); 2..5 = parent 0..3 (E=128)
__device__ float g_usb[6][520];

// Wv/Wo transposed to [k][e] so consumer loads are lane-coalesced (k_setup).
__device__ __align__(16) float g_svT[2][64 * 64];
__device__ __align__(16) float g_soT[2][64 * 64];
__device__ __align__(16) float g_pvT[4][128 * 128];
__device__ __align__(16) float g_poT[4][128 * 128];

__device__ __forceinline__ void LD8(const float* p, float* o) {
  float4 a = ((const float4*)p)[0], b = ((const float4*)p)[1];
  o[0] = a.x; o[1] = a.y; o[2] = a.z; o[3] = a.w;
  o[4] = b.x; o[5] = b.y; o[6] = b.z; o[7] = b.w;
}
__device__ __forceinline__ void fma8(float& acc, const float* x, const float* w) {
#pragma unroll
  for (int i = 0; i < 8; ++i) acc += x[i] * w[i];
}
__device__ __forceinline__ float gelu(float v) {
  return 0.5f * v * (1.0f + erff(v * 0.70710678118654752f));
}

// LayerNorm rows in place: buf [G][E]; one wave per row.
template <int E>
__device__ void ln_rows(float* buf, const float* __restrict__ gg, const float* __restrict__ bb) {
  const int w = threadIdx.x >> 6, lane = threadIdx.x & 63;
  for (int g = w; g < G; g += 4) {
    float* row = buf + g * E;
    float s = 0.f, s2 = 0.f;
    for (int e = lane; e < E; e += 64) { float x = row[e]; s += x; s2 += x * x; }
#pragma unroll
    for (int off = 1; off < 64; off <<= 1) {
      s += __shfl_xor(s, off, 64);
      s2 += __shfl_xor(s2, off, 64);
    }
    float m = s / (float)E;
    float inv = 1.0f / sqrtf(s2 / (float)E - m * m + 1e-5f);
    for (int e = lane; e < E; e += 64) row[e] = (row[e] - m) * inv * gg[e] + bb[e];
  }
}

// ============ setup: per-agg q -> u,sb + Wv/Wo transpose (once) ============
__global__ __launch_bounds__(NT) void k_setup(P p) {
  const int a = blockIdx.x;  // 0..5
  const int tid = threadIdx.x;
  __shared__ float clsb[128];
  __shared__ float qb[128];
  int E;
  const float *Wq, *bq, *cls;
  if (a < 2) {
    E = 64;
    Wq = p.in[I_SWQKV] + (size_t)a * 192 * 64;
    bq = p.in[I_SBQKV] + a * 192;
    cls = p.in[I_SCLS] + a * 64;
  } else {
    E = 128;
    int i = a - 2;
    Wq = p.in[I_PWQKV] + (size_t)i * 384 * 128;
    bq = p.in[I_PBQKV] + i * 384;
    cls = p.in[I_PCLS] + i * 128;
  }
  const int D = E / 4;
  const float scale = (E == 64) ? 0.25f : 0.17677669529663687f;
  if (tid < E) clsb[tid] = cls[tid];
  __syncthreads();
  if (tid < E) {
    float acc = bq[tid];
    const float* w = Wq + (size_t)tid * E;
    for (int k = 0; k < E; k += 8) {
      float wv[8];
      LD8(w + k, wv);
#pragma unroll
      for (int ii = 0; ii < 8; ++ii) acc += clsb[k + ii] * wv[ii];
    }
    qb[tid] = acc;
  }
  __syncthreads();
  if (tid < E) {
    for (int h = 0; h < 4; ++h) {
      float acc = 0.f;
      for (int d = 0; d < D; ++d)
        acc += Wq[(size_t)(E + h * D + d) * E + tid] * qb[h * D + d];
      g_usb[a][h * E + tid] = acc * scale;
    }
  }
  if (tid < 4) {
    float acc = 0.f;
    for (int d = 0; d < D; ++d) acc += qb[tid * D + d] * bq[E + tid * D + d];
    g_usb[a][4 * E + tid] = acc * scale;
  }
  // transpose Wv, Wo for this agg into [k][e]
  if (a < 2) {
    const float* Wv = p.in[I_SWQKV] + (size_t)a * 192 * 64 + 2 * 64 * 64;
    const float* Wo = p.in[I_SWO] + (size_t)a * 64 * 64;
    for (int idx = tid; idx < 64 * 64; idx += NT) {
      int k = idx >> 6, e = idx & 63;
      g_svT[a][idx] = Wv[(size_t)e * 64 + k];
      g_soT[a][idx] = Wo[(size_t)e * 64 + k];
    }
  } else {
    int i = a - 2;
    const float* Wv = p.in[I_PWQKV] + (size_t)i * 384 * 128 + 2 * 128 * 128;
    const float* Wo = p.in[I_PWO] + (size_t)i * 128 * 128;
    for (int idx = tid; idx < 128 * 128; idx += NT) {
      int k = idx >> 7, e = idx & 127;
      g_pvT[i][idx] = Wv[(size_t)e * 128 + k];
      g_poT[i][idx] = Wo[(size_t)e * 128 + k];
    }
  }
}

// Folded CLS-only aggregator over G batches (attn + FFN).
// X layout [g][T][XP]; xbar/partial/ob/hb/mid may alias X (written after X dead).
template <int E, int T, int XP>
__device__ void agg_run(const float* X, const float* clsb,
                        const float* uL, const float* sbL,
                        const float* __restrict__ WvT, const float* __restrict__ bv,
                        const float* __restrict__ WoT, const float* __restrict__ bo,
                        const float* __restrict__ lng, const float* __restrict__ lnb,
                        const float* __restrict__ W1, const float* __restrict__ b1,
                        const float* __restrict__ W2, const float* __restrict__ b2,
                        float* att, float* xbar, float* ob, float* hb, float* mid,
                        float* partial) {
  const int tid = threadIdx.x;
  constexpr int S = T + 1, KS = NT / E, KCH = E / KS;
  constexpr int M1 = (4 * E) / NT, KCH2 = (4 * E) / KS;

  // scores[g][h][s] = sb[h] + x_s . u_h
  for (int i = tid; i < G * 4 * S; i += NT) {
    int s = i % S, hh = (i / S) % 4, g = i / (4 * S);
    const float* u = uL + hh * XP;
    const float* x = (s == 0) ? clsb : (X + (size_t)(g * T + s - 1) * XP);
    float acc = sbL[hh];
    for (int k = 0; k < E; k += 8) {
      float xv[8], uv[8];
      LD8(x + k, xv);
      LD8(u + k, uv);
      fma8(acc, xv, uv);
    }
    att[(g * 4 + hh) * S + s] = acc;
  }
  __syncthreads();
  // softmax over s (serial per row)
  for (int i = tid; i < G * 4; i += NT) {
    float* a = att + i * S;
    float mx = a[0];
    for (int s = 1; s < S; ++s) mx = fmaxf(mx, a[s]);
    float sum = 0.f;
    for (int s = 0; s < S; ++s) { float e = expf(a[s] - mx); a[s] = e; sum += e; }
    float inv = 1.0f / sum;
    for (int s = 0; s < S; ++s) a[s] *= inv;
  }
  __syncthreads();
  // xbar[g][h][k] = sum_s att * x_s[k] -- float4 over k, register-staged so
  // xbar may alias X (X reads complete before writeback barrier).
  constexpr int NI4 = (G * 4 * E) / (4 * NT);
  float4 xacc4[NI4];
#pragma unroll
  for (int n = 0; n < NI4; ++n) {
    int i = tid + n * NT;  // float4 index
    int k4 = i % (E / 4), hh = (i / (E / 4)) % 4, g = i / E;
    const float* a = att + (g * 4 + hh) * S;
    float4 acc = ((const float4*)clsb)[k4];
    float a0 = a[0];
    acc.x *= a0; acc.y *= a0; acc.z *= a0; acc.w *= a0;
    for (int s = 1; s < S; ++s) {
      float as = a[s];
      float4 xv = *(const float4*)(X + (size_t)(g * T + s - 1) * XP + 4 * k4);
      acc.x += as * xv.x; acc.y += as * xv.y;
      acc.z += as * xv.z; acc.w += as * xv.w;
    }
    xacc4[n] = acc;
  }
  __syncthreads();  // all X reads complete; X is dead from here on
#pragma unroll
  for (int n = 0; n < NI4; ++n) ((float4*)xbar)[tid + n * NT] = xacc4[n];
  __syncthreads();
  // o[e] = bv[e] + sum_k Wv[e][k]*xbar[g][hh][k]; WvT[k][e] lane-coalesced
  {
    const int e = tid % E, ks = tid / E, hh = e / (E / 4);
    float acc[G];
#pragma unroll
    for (int g = 0; g < G; ++g) acc[g] = 0.f;
    for (int kc = 0; kc < KCH; kc += 8) {
      float wv[8];
#pragma unroll
      for (int ii = 0; ii < 8; ++ii)
        wv[ii] = WvT[(size_t)(ks * KCH + kc + ii) * E + e];
#pragma unroll
      for (int g = 0; g < G; ++g) {
        float xv[8];
        LD8(xbar + (g * 4 + hh) * E + ks * KCH + kc, xv);
        fma8(acc[g], xv, wv);
      }
    }
#pragma unroll
    for (int g = 0; g < G; ++g) partial[(ks * G + g) * E + e] = acc[g];
  }
  __syncthreads();
  for (int i = tid; i < G * E; i += NT) {
    int e = i % E, g = i / E;
    float v = bv[e];
#pragma unroll
    for (int ks = 0; ks < KS; ++ks) v += partial[(ks * G + g) * E + e];
    ob[g * E + e] = v;
  }
  __syncthreads();
  // h[e] = bo[e] + cls[e] + sum_k Wo[e][k]*o[g][k]; WoT[k][e] lane-coalesced
  {
    const int e = tid % E, ks = tid / E;
    float acc[G];
#pragma unroll
    for (int g = 0; g < G; ++g) acc[g] = 0.f;
    for (int kc = 0; kc < KCH; kc += 8) {
      float wv[8];
#pragma unroll
      for (int ii = 0; ii < 8; ++ii)
        wv[ii] = WoT[(size_t)(ks * KCH + kc + ii) * E + e];
#pragma unroll
      for (int g = 0; g < G; ++g) {
        float xv[8];
        LD8(ob + g * E + ks * KCH + kc, xv);
        fma8(acc[g], xv, wv);
      }
    }
#pragma unroll
    for (int g = 0; g < G; ++g) partial[(ks * G + g) * E + e] = acc[g];
  }
  __syncthreads();
  for (int i = tid; i < G * E; i += NT) {
    int e = i % E, g = i / E;
    float v = bo[e] + clsb[e];
#pragma unroll
    for (int ks = 0; ks < KS; ++ks) v += partial[(ks * G + g) * E + e];
    hb[g * E + e] = v;
  }
  __syncthreads();
  ln_rows<E>(hb, lng, lnb);
  __syncthreads();
  // mid[m] = gelu(h @ W1 + b1)[m]; W1 column access is wave-coalesced
  {
    float acc[M1][G];
#pragma unroll
    for (int r = 0; r < M1; ++r)
#pragma unroll
      for (int g = 0; g < G; ++g) acc[r][g] = 0.f;
    for (int j = 0; j < E; j += 8) {
      float wv[M1][8];
#pragma unroll
      for (int ii = 0; ii < 8; ++ii) {
        if constexpr (M1 == 2) {
          float2 w2 = *(const float2*)(W1 + (size_t)(j + ii) * 4 * E + 2 * tid);
          wv[0][ii] = w2.x;
          wv[1][ii] = w2.y;
        } else {
          wv[0][ii] = W1[(size_t)(j + ii) * 4 * E + tid];
        }
      }
#pragma unroll
      for (int g = 0; g < G; ++g) {
        float xv[8];
        LD8(hb + g * E + j, xv);
#pragma unroll
        for (int r = 0; r < M1; ++r) fma8(acc[r][g], xv, wv[r]);
      }
    }
#pragma unroll
    for (int r = 0; r < M1; ++r) {
      int m = tid * M1 + r;
      float bias = b1[m];
#pragma unroll
      for (int g = 0; g < G; ++g) mid[g * 4 * E + m] = gelu(acc[r][g] + bias);
    }
  }
  __syncthreads();
  // out = LN(h + mid @ W2 + b2) -> ob; W2 column access is wave-coalesced
  {
    const int e = tid % E, ks = tid / E, m0 = ks * KCH2;
    float acc[G];
#pragma unroll
    for (int g = 0; g < G; ++g) acc[g] = 0.f;
    for (int mc = 0; mc < KCH2; mc += 8) {
      float wv[8];
#pragma unroll
      for (int ii = 0; ii < 8; ++ii) wv[ii] = W2[(size_t)(m0 + mc + ii) * E + e];
#pragma unroll
      for (int g = 0; g < G; ++g) {
        float xv[8];
        LD8(mid + g * 4 * E + m0 + mc, xv);
        fma8(acc[g], xv, wv);
      }
    }
#pragma unroll
    for (int g = 0; g < G; ++g) partial[(ks * G + g) * E + e] = acc[g];
  }
  __syncthreads();
  for (int i = tid; i < G * E; i += NT) {
    int e = i % E, g = i / E;
    float v = b2[e] + hb[g * E + e];
#pragma unroll
    for (int ks = 0; ks < KS; ++ks) v += partial[(ks * G + g) * E + e];
    ob[g * E + e] = v;
  }
  __syncthreads();
  ln_rows<E>(ob, lng, lnb);
  __syncthreads();
}

#define PXP 132  // padded parent row (128 + 4): stride == 4 mod 32 banks

// ============ sub body (E=64): align + agg -> vecs[b][AI*64) =====
template <int T, int F0, int AI>
__device__ void sub_body(const P& p, int b0, float* X, float* clsb, float* uL,
                         float* sbL, float* att, float* xbar, float* ob,
                         float* hb, float* mid, float* partial) {
  constexpr int XP = 68;  // padded row (64 + 4): stride == 4 mod 32 banks
  const int tid = threadIdx.x;
  const float* subf = p.in[I_SUB];
  const float* saW = p.in[I_SAW];
  const float* sab = p.in[I_SAB];
  for (int i = tid; i < T * 64; i += NT) {
    int f = i / 64, e = i % 64;
    float bias = sab[(F0 + f) * 64 + e];
    float acc[G];
#pragma unroll
    for (int g = 0; g < G; ++g) acc[g] = bias;
    for (int d = 0; d < 32; d += 8) {
      float wv[8];
#pragma unroll
      for (int ii = 0; ii < 8; ++ii)
        wv[ii] = saW[(size_t)((F0 + f) * 32 + d + ii) * 64 + e];
#pragma unroll
      for (int g = 0; g < G; ++g) {
        float xv[8];
        LD8(subf + (size_t)(b0 + g) * 352 + (F0 + f) * 32 + d, xv);
        fma8(acc[g], xv, wv);
      }
    }
#pragma unroll
    for (int g = 0; g < G; ++g) X[(g * T + f) * XP + e] = acc[g];
  }
  for (int i = tid; i < 4 * 64; i += NT) uL[(i >> 6) * XP + (i & 63)] = g_usb[AI][i];
  if (tid < 4) sbL[tid] = g_usb[AI][256 + tid];
  if (tid < 64) clsb[tid] = p.in[I_SCLS][AI * 64 + tid];
  __syncthreads();

  agg_run<64, T, XP>(X, clsb, uL, sbL,
                     g_svT[AI], p.in[I_SBQKV] + AI * 192 + 128,
                     g_soT[AI], p.in[I_SBO] + AI * 64,
                     p.in[I_SLNG] + AI * 64, p.in[I_SLNB] + AI * 64,
                     p.in[I_SW1] + AI * 64 * 256, p.in[I_SB1] + AI * 256,
                     p.in[I_SW2] + AI * 256 * 64, p.in[I_SB2] + AI * 64,
                     att, xbar, ob, hb, mid, partial);
  for (int i = tid; i < G * 64; i += NT) {
    int e = i % 64, g = i / 64;
    p.vecs[(size_t)(b0 + g) * 384 + AI * 64 + e] = ob[g * 64 + e];
  }
}

// merged sub kernel: y=0 -> tcp.flags (T=8), y=1 -> ip.flags (T=3)
__global__ __launch_bounds__(NT, 4) void k_sub(P p) {
  __shared__ __align__(16) float X[G * 8 * 68];
  __shared__ __align__(16) float clsb[64];
  __shared__ __align__(16) float uL[4 * 68];
  __shared__ __align__(16) float sbL[4];
  __shared__ __align__(16) float att[G * 4 * 9];
  __shared__ __align__(16) float xbar[G * 4 * 64];
  __shared__ __align__(16) float ob[G * 64];
  __shared__ __align__(16) float hb[G * 64];
  __shared__ __align__(16) float mid[G * 256];
  __shared__ __align__(16) float partial[4 * G * 64];
  const int b0 = blockIdx.x * G;
  if (blockIdx.y == 0)
    sub_body<8, 0, 0>(p, b0, X, clsb, uL, sbL, att, xbar, ob, hb, mid, partial);
  else
    sub_body<3, 8, 1>(p, b0, X, clsb, uL, sbL, att, xbar, ob, hb, mid, partial);
}

// parent_al: [:,0] = tcpf @ paW0 + pab0 ; [:,1] = ipf @ paW1 + pab1
__global__ __launch_bounds__(NT, 4) void k_pal(P p) {
  __shared__ __align__(16) float tf[G * 128];  // [g][pi*64+j]
  const int tid = threadIdx.x, b0 = blockIdx.x * G;
  for (int i = tid; i < G * 128; i += NT) {
    int g = i / 128, r = i % 128;
    tf[i] = p.vecs[(size_t)(b0 + g) * 384 + r];
  }
  __syncthreads();
  const int pi = tid >> 7, e = tid & 127;
  const float* paW = p.in[I_PAW];
  float bias = p.in[I_PAB][pi * 128 + e];
  float acc[G];
#pragma unroll
  for (int g = 0; g < G; ++g) acc[g] = bias;
  for (int j = 0; j < 64; j += 8) {
    float wv[8];
#pragma unroll
    for (int ii = 0; ii < 8; ++ii) wv[ii] = paW[(size_t)(pi * 64 + j + ii) * 128 + e];
#pragma unroll
    for (int g = 0; g < G; ++g) {
      float xv[8];
      LD8(tf + g * 128 + pi * 64 + j, xv);
      fma8(acc[g], xv, wv);
    }
  }
#pragma unroll
  for (int g = 0; g < G; ++g)
    p.parent_al[(size_t)(b0 + g) * 256 + pi * 128 + e] = acc[g];
}

// ============ parent body (E=128) ============
// overlay: xbar[0,2048) partial[2048,3072) ob[3072,3584) hb[3584,4096)
// mid[4096,6144)
template <int T, int F, int F0, int PAR, int AI>
__device__ void parent_body(const P& p, int b0, float* arena, float* clsb,
                            float* uL, float* sbL, float* att) {
  const int tid = threadIdx.x;
  float* X = arena;  // [g][T][PXP]
  const float* leaf = p.in[I_LEAF];
  const float* laW = p.in[I_LAW];
  const float* lab = p.in[I_LAB];
  for (int i = tid; i < F * 128; i += NT) {
    int f = i / 128, e = i % 128;
    float bias = lab[(F0 + f) * 128 + e];
    float acc[G];
#pragma unroll
    for (int g = 0; g < G; ++g) acc[g] = bias;
    for (int d = 0; d < 32; d += 8) {
      float wv[8];
#pragma unroll
      for (int ii = 0; ii < 8; ++ii)
        wv[ii] = laW[(size_t)((F0 + f) * 32 + d + ii) * 128 + e];
#pragma unroll
      for (int g = 0; g < G; ++g) {
        float xv[8];
        LD8(leaf + (size_t)(b0 + g) * 1088 + (F0 + f) * 32 + d, xv);
        fma8(acc[g], xv, wv);
      }
    }
#pragma unroll
    for (int g = 0; g < G; ++g) X[(g * T + f) * PXP + e] = acc[g];
  }
  if constexpr (PAR >= 0) {
    for (int i = tid; i < G * 128; i += NT) {
      int g = i / 128, e = i % 128;
      X[(g * T + T - 1) * PXP + e] = p.parent_al[(size_t)(b0 + g) * 256 + PAR * 128 + e];
    }
  }
  for (int i = tid; i < 4 * 128; i += NT) uL[(i >> 7) * PXP + (i & 127)] = g_usb[2 + AI][i];
  if (tid < 4) sbL[tid] = g_usb[2 + AI][512 + tid];
  if (tid < 128) clsb[tid] = p.in[I_PCLS][AI * 128 + tid];
  __syncthreads();

  float* xbar = arena;
  float* partial = arena + 2048;
  float* ob = arena + 3072;
  float* hb = arena + 3584;
  float* mid = arena + 4096;
  agg_run<128, T, PXP>(X, clsb, uL, sbL,
                       g_pvT[AI], p.in[I_PBQKV] + AI * 384 + 256,
                       g_poT[AI], p.in[I_PBO] + AI * 128,
                       p.in[I_PLNG] + AI * 128, p.in[I_PLNB] + AI * 128,
                       p.in[I_PW1] + (size_t)AI * 128 * 512, p.in[I_PB1] + AI * 512,
                       p.in[I_PW2] + (size_t)AI * 512 * 128, p.in[I_PB2] + AI * 128,
                       att, xbar, ob, hb, mid, partial);
  for (int i = tid; i < G * 128; i += NT) {
    int e = i % 128, g = i / 128;
    p.vecs[(size_t)(b0 + g) * 384 + AI * 128 + e] = ob[g * 128 + e];
  }
}

// merged parent kernel: y=0 eth(T=8), y=1 ip(T=12), y=2 tcp(T=16)
__global__ __launch_bounds__(NT, 4) void k_parent(P p) {
  __shared__ __align__(16) float arena[G * 16 * PXP];  // 8448 >= overlay 6144
  __shared__ __align__(16) float clsb[128];
  __shared__ __align__(16) float uL[4 * PXP];
  __shared__ __align__(16) float sbL[4];
  __shared__ __align__(16) float att[G * 4 * 17];
  const int b0 = blockIdx.x * G;
  if (blockIdx.y == 0)
    parent_body<8, 8, 0, -1, 0>(p, b0, arena, clsb, uL, sbL, att);
  else if (blockIdx.y == 1)
    parent_body<12, 11, 8, 1, 1>(p, b0, arena, clsb, uL, sbL, att);
  else
    parent_body<16, 15, 19, 0, 2>(p, b0, arena, clsb, uL, sbL, att);
}

// ===================== pkt agg + classifier =====================
__global__ __launch_bounds__(NT, 4) void k_pkt(P p) {
  __shared__ __align__(16) float arena[6144];  // X 3*G*PXP=1584 < overlay 6144
  __shared__ __align__(16) float clsb[128];
  __shared__ __align__(16) float uL[4 * PXP];
  __shared__ __align__(16) float sbL[4];
  __shared__ __align__(16) float att[G * 4 * 4];
  const int tid = threadIdx.x, b0 = blockIdx.x * G;
  float* X = arena;  // [g][3][PXP]

  for (int i = tid; i < 3 * G * 128; i += NT) {
    int e = i % 128, g = (i / 128) % G, t = i / (G * 128);
    X[(g * 3 + t) * PXP + e] = p.vecs[(size_t)(b0 + g) * 384 + t * 128 + e];
  }
  for (int i = tid; i < 4 * 128; i += NT) uL[(i >> 7) * PXP + (i & 127)] = g_usb[5][i];
  if (tid < 4) sbL[tid] = g_usb[5][512 + tid];
  if (tid < 128) clsb[tid] = p.in[I_PCLS][3 * 128 + tid];
  __syncthreads();

  float* xbar = arena;
  float* partial = arena + 2048;
  float* ob = arena + 3072;
  float* hb = arena + 3584;
  float* mid = arena + 4096;
  agg_run<128, 3, PXP>(X, clsb, uL, sbL,
                       g_pvT[3], p.in[I_PBQKV] + 3 * 384 + 256,
                       g_poT[3], p.in[I_PBO] + 3 * 128,
                       p.in[I_PLNG] + 3 * 128, p.in[I_PLNB] + 3 * 128,
                       p.in[I_PW1] + (size_t)3 * 128 * 512, p.in[I_PB1] + 3 * 512,
                       p.in[I_PW2] + (size_t)3 * 512 * 128, p.in[I_PB2] + 3 * 128,
                       att, xbar, ob, hb, mid, partial);

  if (tid < G * 2) {
    int g = tid >> 1, c = tid & 1;
    const float* cw = p.in[I_CLFW];
    float acc = p.in[I_CLFB][c];
    for (int j = 0; j < 128; ++j) acc += ob[g * 128 + j] * cw[j * 2 + c];
    p.out[(size_t)(b0 + g) * 2 + c] = acc;
  }
}

extern "C" void kernel_launch(void* const* d_in, const int* in_sizes, int n_in,
                              void* d_out, int out_size, void* d_ws, size_t ws_size,
                              hipStream_t stream) {
  P p;
  for (int i = 0; i < 32; ++i) p.in[i] = (const float*)d_in[i];
  const int B = in_sizes[0] / (34 * 32);
  float* ws = (float*)d_ws;
  p.parent_al = ws;                        // B*256 floats
  p.vecs = ws + (size_t)B * 256;           // B*384 floats
  p.out = (float*)d_out;
  const dim3 blk(NT);

  k_setup<<<dim3(6), blk, 0, stream>>>(p);
  k_sub<<<dim3(B / G, 2), blk, 0, stream>>>(p);
  k_pal<<<dim3(B / G), blk, 0, stream>>>(p);
  k_parent<<<dim3(B / G, 3), blk, 0, stream>>>(p);
  k_pkt<<<dim3(B / G), blk, 0, stream>>>(p);
}

// Round 16
// 921.928 us; speedup vs baseline: 1.0574x; 1.0574x over previous
//
#include <hip/hip_runtime.h>
#include <math.h>

#define G 4
#define NT 256

// fp32 problem (validated). G=4 batches per block.
//
// Hard-won configuration facts (measured r2-r15):
//  - G=4, NT=256, __launch_bounds__(256,4). NT=512 pins VGPR at the cap ->
//    GBs of scratch spill (r3/r4). G=2 -> invisible scratch (r7).
//  - Scratch demotion triggers: SEQUENTIAL agg bodies in one path (r8) and
//    MIXED sub/parent templates in one kernel (r12 k_lvl1). SAME-template
//    branching on blockIdx.y is clean (r2, r14 merged parents: FETCH 35MB).
//  - Weight access per-wave COALESCED (lane = fastest dim). r6: gathers +50%.
//    r10: Wv/Wo gather->coalesced (k_setup transpose) won 196->181us.
//  - attn/FFN kernel split REGRESSED (r11). Wave-parallel softmax REGRESSED
//    (r12/r13, shfl-chain latency > serial for S<=17): serial softmax kept.
//    float4 xbar NEUTRAL-NEGATIVE (r15): scalar xbar kept.
//  - Partial/reduce scheme for Wv/Wo/W2 kept (direct mapping would 2-4x
//    weight L2 traffic).
//  - X layout [g][s][XP], XP=68/132 (row stride == 4 mod 32 banks).
//  - q/u/sb + WvT/WoT precomputed once per launch in k_setup.
//  - THIS ROUND (r14 base + one change): k_pal folded into k_parent y=1/y=2
//    (inline PAR-row GEMV from vecs slot 0, r13's verified dataflow);
//    parent y=0 outputs to parent_al[0:128) so tcpf/ipf stay live;
//    k_pkt reads eth from parent_al. Launches 5 -> 4.

enum {
  I_LEAF = 0, I_SUB, I_SAW, I_SAB, I_LAW, I_LAB, I_PAW, I_PAB,
  I_SCLS, I_SWQKV, I_SBQKV, I_SWO, I_SBO, I_SLNG, I_SLNB, I_SW1, I_SB1, I_SW2, I_SB2,
  I_PCLS, I_PWQKV, I_PBQKV, I_PWO, I_PBO, I_PLNG, I_PLNB, I_PW1, I_PB1, I_PW2, I_PB2,
  I_CLFW, I_CLFB
};

struct P {
  const float* in[32];
  float* parent_al;  // ws [B][2][128]; [0:128) = parent0 (eth) final vec
  float* vecs;       // ws [B][3][128]; [0:128)=tcpf|ipf, [128:384)=ip|tcp vecs
  float* out;        // [B][2]
};

// per-aggregator precomputed query side: u[4][E] then sb[4] at offset 4*E.
// aggs: 0,1 = sub (E=64); 2..5 = parent 0..3 (E=128)
__device__ float g_usb[6][520];

// Wv/Wo transposed to [k][e] so consumer loads are lane-coalesced (k_setup).
__device__ __align__(16) float g_svT[2][64 * 64];
__device__ __align__(16) float g_soT[2][64 * 64];
__device__ __align__(16) float g_pvT[4][128 * 128];
__device__ __align__(16) float g_poT[4][128 * 128];

__device__ __forceinline__ void LD8(const float* p, float* o) {
  float4 a = ((const float4*)p)[0], b = ((const float4*)p)[1];
  o[0] = a.x; o[1] = a.y; o[2] = a.z; o[3] = a.w;
  o[4] = b.x; o[5] = b.y; o[6] = b.z; o[7] = b.w;
}
__device__ __forceinline__ void fma8(float& acc, const float* x, const float* w) {
#pragma unroll
  for (int i = 0; i < 8; ++i) acc += x[i] * w[i];
}
__device__ __forceinline__ float gelu(float v) {
  return 0.5f * v * (1.0f + erff(v * 0.70710678118654752f));
}

// LayerNorm rows in place: buf [G][E]; one wave per row.
template <int E>
__device__ void ln_rows(float* buf, const float* __restrict__ gg, const float* __restrict__ bb) {
  const int w = threadIdx.x >> 6, lane = threadIdx.x & 63;
  for (int g = w; g < G; g += 4) {
    float* row = buf + g * E;
    float s = 0.f, s2 = 0.f;
    for (int e = lane; e < E; e += 64) { float x = row[e]; s += x; s2 += x * x; }
#pragma unroll
    for (int off = 1; off < 64; off <<= 1) {
      s += __shfl_xor(s, off, 64);
      s2 += __shfl_xor(s2, off, 64);
    }
    float m = s / (float)E;
    float inv = 1.0f / sqrtf(s2 / (float)E - m * m + 1e-5f);
    for (int e = lane; e < E; e += 64) row[e] = (row[e] - m) * inv * gg[e] + bb[e];
  }
}

// ============ setup: per-agg q -> u,sb + Wv/Wo transpose (once) ============
__global__ __launch_bounds__(NT) void k_setup(P p) {
  const int a = blockIdx.x;  // 0..5
  const int tid = threadIdx.x;
  __shared__ float clsb[128];
  __shared__ float qb[128];
  int E;
  const float *Wq, *bq, *cls;
  if (a < 2) {
    E = 64;
    Wq = p.in[I_SWQKV] + (size_t)a * 192 * 64;
    bq = p.in[I_SBQKV] + a * 192;
    cls = p.in[I_SCLS] + a * 64;
  } else {
    E = 128;
    int i = a - 2;
    Wq = p.in[I_PWQKV] + (size_t)i * 384 * 128;
    bq = p.in[I_PBQKV] + i * 384;
    cls = p.in[I_PCLS] + i * 128;
  }
  const int D = E / 4;
  const float scale = (E == 64) ? 0.25f : 0.17677669529663687f;
  if (tid < E) clsb[tid] = cls[tid];
  __syncthreads();
  if (tid < E) {
    float acc = bq[tid];
    const float* w = Wq + (size_t)tid * E;
    for (int k = 0; k < E; k += 8) {
      float wv[8];
      LD8(w + k, wv);
#pragma unroll
      for (int ii = 0; ii < 8; ++ii) acc += clsb[k + ii] * wv[ii];
    }
    qb[tid] = acc;
  }
  __syncthreads();
  if (tid < E) {
    for (int h = 0; h < 4; ++h) {
      float acc = 0.f;
      for (int d = 0; d < D; ++d)
        acc += Wq[(size_t)(E + h * D + d) * E + tid] * qb[h * D + d];
      g_usb[a][h * E + tid] = acc * scale;
    }
  }
  if (tid < 4) {
    float acc = 0.f;
    for (int d = 0; d < D; ++d) acc += qb[tid * D + d] * bq[E + tid * D + d];
    g_usb[a][4 * E + tid] = acc * scale;
  }
  // transpose Wv, Wo for this agg into [k][e]
  if (a < 2) {
    const float* Wv = p.in[I_SWQKV] + (size_t)a * 192 * 64 + 2 * 64 * 64;
    const float* Wo = p.in[I_SWO] + (size_t)a * 64 * 64;
    for (int idx = tid; idx < 64 * 64; idx += NT) {
      int k = idx >> 6, e = idx & 63;
      g_svT[a][idx] = Wv[(size_t)e * 64 + k];
      g_soT[a][idx] = Wo[(size_t)e * 64 + k];
    }
  } else {
    int i = a - 2;
    const float* Wv = p.in[I_PWQKV] + (size_t)i * 384 * 128 + 2 * 128 * 128;
    const float* Wo = p.in[I_PWO] + (size_t)i * 128 * 128;
    for (int idx = tid; idx < 128 * 128; idx += NT) {
      int k = idx >> 7, e = idx & 127;
      g_pvT[i][idx] = Wv[(size_t)e * 128 + k];
      g_poT[i][idx] = Wo[(size_t)e * 128 + k];
    }
  }
}

// Folded CLS-only aggregator over G batches (attn + FFN) — exact r14 form.
// X layout [g][T][XP]; xbar/partial/ob/hb/mid may alias X (written after X dead).
template <int E, int T, int XP>
__device__ void agg_run(const float* X, const float* clsb,
                        const float* uL, const float* sbL,
                        const float* __restrict__ WvT, const float* __restrict__ bv,
                        const float* __restrict__ WoT, const float* __restrict__ bo,
                        const float* __restrict__ lng, const float* __restrict__ lnb,
                        const float* __restrict__ W1, const float* __restrict__ b1,
                        const float* __restrict__ W2, const float* __restrict__ b2,
                        float* att, float* xbar, float* ob, float* hb, float* mid,
                        float* partial) {
  const int tid = threadIdx.x;
  constexpr int S = T + 1, KS = NT / E, KCH = E / KS;
  constexpr int M1 = (4 * E) / NT, KCH2 = (4 * E) / KS;

  // scores[g][h][s] = sb[h] + x_s . u_h
  for (int i = tid; i < G * 4 * S; i += NT) {
    int s = i % S, hh = (i / S) % 4, g = i / (4 * S);
    const float* u = uL + hh * XP;
    const float* x = (s == 0) ? clsb : (X + (size_t)(g * T + s - 1) * XP);
    float acc = sbL[hh];
    for (int k = 0; k < E; k += 8) {
      float xv[8], uv[8];
      LD8(x + k, xv);
      LD8(u + k, uv);
      fma8(acc, xv, uv);
    }
    att[(g * 4 + hh) * S + s] = acc;
  }
  __syncthreads();
  // softmax over s (serial per row)
  for (int i = tid; i < G * 4; i += NT) {
    float* a = att + i * S;
    float mx = a[0];
    for (int s = 1; s < S; ++s) mx = fmaxf(mx, a[s]);
    float sum = 0.f;
    for (int s = 0; s < S; ++s) { float e = expf(a[s] - mx); a[s] = e; sum += e; }
    float inv = 1.0f / sum;
    for (int s = 0; s < S; ++s) a[s] *= inv;
  }
  __syncthreads();
  // xbar[g][h][k] = sum_s att * x_s[k] -- register-staged so xbar may alias X
  constexpr int NI = (G * 4 * E) / NT;
  float xacc[NI];
#pragma unroll
  for (int n = 0; n < NI; ++n) {
    int i = tid + n * NT;
    int k = i % E, hh = (i / E) % 4, g = i / (4 * E);
    const float* a = att + (g * 4 + hh) * S;
    float acc = a[0] * clsb[k];
    for (int s = 1; s < S; ++s) acc += a[s] * X[(size_t)(g * T + s - 1) * XP + k];
    xacc[n] = acc;
  }
  __syncthreads();  // all X reads complete; X is dead from here on
#pragma unroll
  for (int n = 0; n < NI; ++n) xbar[tid + n * NT] = xacc[n];
  __syncthreads();
  // o[e] = bv[e] + sum_k Wv[e][k]*xbar[g][hh][k]; WvT[k][e] lane-coalesced
  {
    const int e = tid % E, ks = tid / E, hh = e / (E / 4);
    float acc[G];
#pragma unroll
    for (int g = 0; g < G; ++g) acc[g] = 0.f;
    for (int kc = 0; kc < KCH; kc += 8) {
      float wv[8];
#pragma unroll
      for (int ii = 0; ii < 8; ++ii)
        wv[ii] = WvT[(size_t)(ks * KCH + kc + ii) * E + e];
#pragma unroll
      for (int g = 0; g < G; ++g) {
        float xv[8];
        LD8(xbar + (g * 4 + hh) * E + ks * KCH + kc, xv);
        fma8(acc[g], xv, wv);
      }
    }
#pragma unroll
    for (int g = 0; g < G; ++g) partial[(ks * G + g) * E + e] = acc[g];
  }
  __syncthreads();
  for (int i = tid; i < G * E; i += NT) {
    int e = i % E, g = i / E;
    float v = bv[e];
#pragma unroll
    for (int ks = 0; ks < KS; ++ks) v += partial[(ks * G + g) * E + e];
    ob[g * E + e] = v;
  }
  __syncthreads();
  // h[e] = bo[e] + cls[e] + sum_k Wo[e][k]*o[g][k]; WoT[k][e] lane-coalesced
  {
    const int e = tid % E, ks = tid / E;
    float acc[G];
#pragma unroll
    for (int g = 0; g < G; ++g) acc[g] = 0.f;
    for (int kc = 0; kc < KCH; kc += 8) {
      float wv[8];
#pragma unroll
      for (int ii = 0; ii < 8; ++ii)
        wv[ii] = WoT[(size_t)(ks * KCH + kc + ii) * E + e];
#pragma unroll
      for (int g = 0; g < G; ++g) {
        float xv[8];
        LD8(ob + g * E + ks * KCH + kc, xv);
        fma8(acc[g], xv, wv);
      }
    }
#pragma unroll
    for (int g = 0; g < G; ++g) partial[(ks * G + g) * E + e] = acc[g];
  }
  __syncthreads();
  for (int i = tid; i < G * E; i += NT) {
    int e = i % E, g = i / E;
    float v = bo[e] + clsb[e];
#pragma unroll
    for (int ks = 0; ks < KS; ++ks) v += partial[(ks * G + g) * E + e];
    hb[g * E + e] = v;
  }
  __syncthreads();
  ln_rows<E>(hb, lng, lnb);
  __syncthreads();
  // mid[m] = gelu(h @ W1 + b1)[m]; W1 column access is wave-coalesced
  {
    float acc[M1][G];
#pragma unroll
    for (int r = 0; r < M1; ++r)
#pragma unroll
      for (int g = 0; g < G; ++g) acc[r][g] = 0.f;
    for (int j = 0; j < E; j += 8) {
      float wv[M1][8];
#pragma unroll
      for (int ii = 0; ii < 8; ++ii) {
        if constexpr (M1 == 2) {
          float2 w2 = *(const float2*)(W1 + (size_t)(j + ii) * 4 * E + 2 * tid);
          wv[0][ii] = w2.x;
          wv[1][ii] = w2.y;
        } else {
          wv[0][ii] = W1[(size_t)(j + ii) * 4 * E + tid];
        }
      }
#pragma unroll
      for (int g = 0; g < G; ++g) {
        float xv[8];
        LD8(hb + g * E + j, xv);
#pragma unroll
        for (int r = 0; r < M1; ++r) fma8(acc[r][g], xv, wv[r]);
      }
    }
#pragma unroll
    for (int r = 0; r < M1; ++r) {
      int m = tid * M1 + r;
      float bias = b1[m];
#pragma unroll
      for (int g = 0; g < G; ++g) mid[g * 4 * E + m] = gelu(acc[r][g] + bias);
    }
  }
  __syncthreads();
  // out = LN(h + mid @ W2 + b2) -> ob; W2 column access is wave-coalesced
  {
    const int e = tid % E, ks = tid / E, m0 = ks * KCH2;
    float acc[G];
#pragma unroll
    for (int g = 0; g < G; ++g) acc[g] = 0.f;
    for (int mc = 0; mc < KCH2; mc += 8) {
      float wv[8];
#pragma unroll
      for (int ii = 0; ii < 8; ++ii) wv[ii] = W2[(size_t)(m0 + mc + ii) * E + e];
#pragma unroll
      for (int g = 0; g < G; ++g) {
        float xv[8];
        LD8(mid + g * 4 * E + m0 + mc, xv);
        fma8(acc[g], xv, wv);
      }
    }
#pragma unroll
    for (int g = 0; g < G; ++g) partial[(ks * G + g) * E + e] = acc[g];
  }
  __syncthreads();
  for (int i = tid; i < G * E; i += NT) {
    int e = i % E, g = i / E;
    float v = b2[e] + hb[g * E + e];
#pragma unroll
    for (int ks = 0; ks < KS; ++ks) v += partial[(ks * G + g) * E + e];
    ob[g * E + e] = v;
  }
  __syncthreads();
  ln_rows<E>(ob, lng, lnb);
  __syncthreads();
}

#define PXP 132  // padded parent row (128 + 4): stride == 4 mod 32 banks

// ============ sub body (E=64): align + agg -> vecs[b][AI*64) =====
template <int T, int F0, int AI>
__device__ void sub_body(const P& p, int b0, float* X, float* clsb, float* uL,
                         float* sbL, float* att, float* xbar, float* ob,
                         float* hb, float* mid, float* partial) {
  constexpr int XP = 68;  // padded row (64 + 4): stride == 4 mod 32 banks
  const int tid = threadIdx.x;
  const float* subf = p.in[I_SUB];
  const float* saW = p.in[I_SAW];
  const float* sab = p.in[I_SAB];
  for (int i = tid; i < T * 64; i += NT) {
    int f = i / 64, e = i % 64;
    float bias = sab[(F0 + f) * 64 + e];
    float acc[G];
#pragma unroll
    for (int g = 0; g < G; ++g) acc[g] = bias;
    for (int d = 0; d < 32; d += 8) {
      float wv[8];
#pragma unroll
      for (int ii = 0; ii < 8; ++ii)
        wv[ii] = saW[(size_t)((F0 + f) * 32 + d + ii) * 64 + e];
#pragma unroll
      for (int g = 0; g < G; ++g) {
        float xv[8];
        LD8(subf + (size_t)(b0 + g) * 352 + (F0 + f) * 32 + d, xv);
        fma8(acc[g], xv, wv);
      }
    }
#pragma unroll
    for (int g = 0; g < G; ++g) X[(g * T + f) * XP + e] = acc[g];
  }
  for (int i = tid; i < 4 * 64; i += NT) uL[(i >> 6) * XP + (i & 63)] = g_usb[AI][i];
  if (tid < 4) sbL[tid] = g_usb[AI][256 + tid];
  if (tid < 64) clsb[tid] = p.in[I_SCLS][AI * 64 + tid];
  __syncthreads();

  agg_run<64, T, XP>(X, clsb, uL, sbL,
                     g_svT[AI], p.in[I_SBQKV] + AI * 192 + 128,
                     g_soT[AI], p.in[I_SBO] + AI * 64,
                     p.in[I_SLNG] + AI * 64, p.in[I_SLNB] + AI * 64,
                     p.in[I_SW1] + AI * 64 * 256, p.in[I_SB1] + AI * 256,
                     p.in[I_SW2] + AI * 256 * 64, p.in[I_SB2] + AI * 64,
                     att, xbar, ob, hb, mid, partial);
  for (int i = tid; i < G * 64; i += NT) {
    int e = i % 64, g = i / 64;
    p.vecs[(size_t)(b0 + g) * 384 + AI * 64 + e] = ob[g * 64 + e];
  }
}

// merged sub kernel: y=0 -> tcp.flags (T=8), y=1 -> ip.flags (T=3)
__global__ __launch_bounds__(NT, 4) void k_sub(P p) {
  __shared__ __align__(16) float X[G * 8 * 68];
  __shared__ __align__(16) float clsb[64];
  __shared__ __align__(16) float uL[4 * 68];
  __shared__ __align__(16) float sbL[4];
  __shared__ __align__(16) float att[G * 4 * 9];
  __shared__ __align__(16) float xbar[G * 4 * 64];
  __shared__ __align__(16) float ob[G * 64];
  __shared__ __align__(16) float hb[G * 64];
  __shared__ __align__(16) float mid[G * 256];
  __shared__ __align__(16) float partial[4 * G * 64];
  const int b0 = blockIdx.x * G;
  if (blockIdx.y == 0)
    sub_body<8, 0, 0>(p, b0, X, clsb, uL, sbL, att, xbar, ob, hb, mid, partial);
  else
    sub_body<3, 8, 1>(p, b0, X, clsb, uL, sbL, att, xbar, ob, hb, mid, partial);
}

// ============ parent body (E=128), pal GEMV folded for PI>=0 ============
// PI: -1 = no parent row; 0 = tcpf@paW0 (tcp agg); 1 = ipf@paW1 (ip agg).
// AI==0 outputs to parent_al[0:128); else to vecs[AI*128 : +128).
// overlay: xbar[0,2048) partial[2048,3072) ob[3072,3584) hb[3584,4096)
// mid[4096,6144)
template <int T, int F, int F0, int PI, int AI>
__device__ void parent_body(const P& p, int b0, float* arena, float* clsb,
                            float* uL, float* sbL, float* att, float* tf) {
  const int tid = threadIdx.x;
  float* X = arena;  // [g][T][PXP]
  const float* leaf = p.in[I_LEAF];
  const float* laW = p.in[I_LAW];
  const float* lab = p.in[I_LAB];
  if constexpr (PI >= 0) {
    // stage f = final subfield vec (tcpf or ipf) from vecs slot 0
    for (int i = tid; i < G * 64; i += NT)
      tf[i] = p.vecs[(size_t)(b0 + i / 64) * 384 + PI * 64 + (i & 63)];
  }
  for (int i = tid; i < F * 128; i += NT) {
    int f = i / 128, e = i % 128;
    float bias = lab[(F0 + f) * 128 + e];
    float acc[G];
#pragma unroll
    for (int g = 0; g < G; ++g) acc[g] = bias;
    for (int d = 0; d < 32; d += 8) {
      float wv[8];
#pragma unroll
      for (int ii = 0; ii < 8; ++ii)
        wv[ii] = laW[(size_t)((F0 + f) * 32 + d + ii) * 128 + e];
#pragma unroll
      for (int g = 0; g < G; ++g) {
        float xv[8];
        LD8(leaf + (size_t)(b0 + g) * 1088 + (F0 + f) * 32 + d, xv);
        fma8(acc[g], xv, wv);
      }
    }
#pragma unroll
    for (int g = 0; g < G; ++g) X[(g * T + f) * PXP + e] = acc[g];
  }
  if constexpr (PI >= 0) {
    __syncthreads();  // tf visible to all threads
    const float* paW = p.in[I_PAW] + (size_t)PI * 64 * 128;
    const float* pab = p.in[I_PAB] + PI * 128;
    for (int i = tid; i < G * 128; i += NT) {
      int g = i / 128, e = i % 128;
      float acc = pab[e];
      const float* f = tf + g * 64;
      for (int j = 0; j < 64; j += 8) {
        float wv[8], fv[8];
        LD8(f + j, fv);  // broadcast (same addr across e-lanes)
#pragma unroll
        for (int ii = 0; ii < 8; ++ii) wv[ii] = paW[(size_t)(j + ii) * 128 + e];
        fma8(acc, fv, wv);
      }
      X[(g * T + T - 1) * PXP + e] = acc;
    }
  }
  for (int i = tid; i < 4 * 128; i += NT) uL[(i >> 7) * PXP + (i & 127)] = g_usb[2 + AI][i];
  if (tid < 4) sbL[tid] = g_usb[2 + AI][512 + tid];
  if (tid < 128) clsb[tid] = p.in[I_PCLS][AI * 128 + tid];
  __syncthreads();

  float* xbar = arena;
  float* partial = arena + 2048;
  float* ob = arena + 3072;
  float* hb = arena + 3584;
  float* mid = arena + 4096;
  agg_run<128, T, PXP>(X, clsb, uL, sbL,
                       g_pvT[AI], p.in[I_PBQKV] + AI * 384 + 256,
                       g_poT[AI], p.in[I_PBO] + AI * 128,
                       p.in[I_PLNG] + AI * 128, p.in[I_PLNB] + AI * 128,
                       p.in[I_PW1] + (size_t)AI * 128 * 512, p.in[I_PB1] + AI * 512,
                       p.in[I_PW2] + (size_t)AI * 512 * 128, p.in[I_PB2] + AI * 128,
                       att, xbar, ob, hb, mid, partial);
  for (int i = tid; i < G * 128; i += NT) {
    int e = i % 128, g = i / 128;
    if constexpr (AI == 0)
      p.parent_al[(size_t)(b0 + g) * 256 + e] = ob[g * 128 + e];
    else
      p.vecs[(size_t)(b0 + g) * 384 + AI * 128 + e] = ob[g * 128 + e];
  }
}

// merged parent kernel: y=0 eth(T=8), y=1 ip(T=12,+ipf row), y=2 tcp(T=16,+tcpf row)
__global__ __launch_bounds__(NT, 4) void k_parent(P p) {
  __shared__ __align__(16) float arena[G * 16 * PXP];  // 8448 >= overlay 6144
  __shared__ __align__(16) float clsb[128];
  __shared__ __align__(16) float uL[4 * PXP];
  __shared__ __align__(16) float sbL[4];
  __shared__ __align__(16) float att[G * 4 * 17];
  __shared__ __align__(16) float tf[G * 64];
  const int b0 = blockIdx.x * G;
  if (blockIdx.y == 0)
    parent_body<8, 8, 0, -1, 0>(p, b0, arena, clsb, uL, sbL, att, tf);
  else if (blockIdx.y == 1)
    parent_body<12, 11, 8, 1, 1>(p, b0, arena, clsb, uL, sbL, att, tf);
  else
    parent_body<16, 15, 19, 0, 2>(p, b0, arena, clsb, uL, sbL, att, tf);
}

// ===================== pkt agg + classifier =====================
__global__ __launch_bounds__(NT, 4) void k_pkt(P p) {
  __shared__ __align__(16) float arena[6144];  // X 3*G*PXP=1584 < overlay 6144
  __shared__ __align__(16) float clsb[128];
  __shared__ __align__(16) float uL[4 * PXP];
  __shared__ __align__(16) float sbL[4];
  __shared__ __align__(16) float att[G * 4 * 4];
  const int tid = threadIdx.x, b0 = blockIdx.x * G;
  float* X = arena;  // [g][3][PXP]: t=0 eth (parent_al), t=1 ip, t=2 tcp

  for (int i = tid; i < 3 * G * 128; i += NT) {
    int e = i % 128, g = (i / 128) % G, t = i / (G * 128);
    float v = (t == 0) ? p.parent_al[(size_t)(b0 + g) * 256 + e]
                       : p.vecs[(size_t)(b0 + g) * 384 + t * 128 + e];
    X[(g * 3 + t) * PXP + e] = v;
  }
  for (int i = tid; i < 4 * 128; i += NT) uL[(i >> 7) * PXP + (i & 127)] = g_usb[5][i];
  if (tid < 4) sbL[tid] = g_usb[5][512 + tid];
  if (tid < 128) clsb[tid] = p.in[I_PCLS][3 * 128 + tid];
  __syncthreads();

  float* xbar = arena;
  float* partial = arena + 2048;
  float* ob = arena + 3072;
  float* hb = arena + 3584;
  float* mid = arena + 4096;
  agg_run<128, 3, PXP>(X, clsb, uL, sbL,
                       g_pvT[3], p.in[I_PBQKV] + 3 * 384 + 256,
                       g_poT[3], p.in[I_PBO] + 3 * 128,
                       p.in[I_PLNG] + 3 * 128, p.in[I_PLNB] + 3 * 128,
                       p.in[I_PW1] + (size_t)3 * 128 * 512, p.in[I_PB1] + 3 * 512,
                       p.in[I_PW2] + (size_t)3 * 512 * 128, p.in[I_PB2] + 3 * 128,
                       att, xbar, ob, hb, mid, partial);

  if (tid < G * 2) {
    int g = tid >> 1, c = tid & 1;
    const float* cw = p.in[I_CLFW];
    float acc = p.in[I_CLFB][c];
    for (int j = 0; j < 128; ++j) acc += ob[g * 128 + j] * cw[j * 2 + c];
    p.out[(size_t)(b0 + g) * 2 + c] = acc;
  }
}

extern "C" void kernel_launch(void* const* d_in, const int* in_sizes, int n_in,
                              void* d_out, int out_size, void* d_ws, size_t ws_size,
                              hipStream_t stream) {
  P p;
  for (int i = 0; i < 32; ++i) p.in[i] = (const float*)d_in[i];
  const int B = in_sizes[0] / (34 * 32);
  float* ws = (float*)d_ws;
  p.parent_al = ws;                        // B*256 floats
  p.vecs = ws + (size_t)B * 256;           // B*384 floats
  p.out = (float*)d_out;
  const dim3 blk(NT);

  k_setup<<<dim3(6), blk, 0, stream>>>(p);
  k_sub<<<dim3(B / G, 2), blk, 0, stream>>>(p);
  k_parent<<<dim3(B / G, 3), blk, 0, stream>>>(p);
  k_pkt<<<dim3(B / G), blk, 0, stream>>>(p);
}